// Round 1
// baseline (2969.045 us; speedup 1.0000x reference)
//
#include <hip/hip_runtime.h>

#define T_LEN 512
#define HID   40
#define G4    160   // 4*H
#define BT    8     // sequences per block
#define ACT_LD 164  // padded act row stride (bank-conflict-free writes)

__device__ __forceinline__ float fast_rcp(float v) { return __builtin_amdgcn_rcpf(v); }

// sigmoid, or tanh via tanh(x) = 2*sigmoid(2x)-1
__device__ __forceinline__ float sigm_like(float v, bool isg) {
    float xx = isg ? 2.f * v : v;
    float e  = __expf(-xx);
    float s  = fast_rcp(1.f + e);
    return isg ? 2.f * s - 1.f : s;
}
__device__ __forceinline__ float tanh_fast(float v) {
    float e = __expf(-2.f * v);
    return 2.f * fast_rcp(1.f + e) - 1.f;
}

__device__ __forceinline__ float cell_update(const float* sAct, int b, int u, float& c) {
    float i = sAct[b * ACT_LD + u];
    float f = sAct[b * ACT_LD + 40 + u];
    float g = sAct[b * ACT_LD + 80 + u];
    float o = sAct[b * ACT_LD + 120 + u];
    c = f * c + i * g;
    return o * tanh_fast(c);
}

// One layer's gate matmul: thread (jp,kq) computes partial dots for its 3 j-rows
// over its K-quarter for all 8 sequences, shfl-transpose-reduces across kq so
// lane kq ends owning full sums for sequences {bown, bown+1}, activates, writes LDS.
template <int SLICE, int LD>
__device__ __forceinline__ void gate_matmul(const float* __restrict__ Bl,
                                            const float (&W)[3][SLICE],
                                            const float (&bias)[3],
                                            const bool (&isg)[3],
                                            const bool (&jv)[3],
                                            const int (&jrow)[3],
                                            float* __restrict__ sAct,
                                            int kq, int bown) {
    float acc[3][BT];
#pragma unroll
    for (int jj = 0; jj < 3; ++jj)
#pragma unroll
        for (int b = 0; b < BT; ++b) acc[jj][b] = 0.f;

    const int k0 = kq * SLICE;
#pragma unroll
    for (int c2 = 0; c2 < SLICE / 4; ++c2) {
        float4 hv[BT];
#pragma unroll
        for (int b = 0; b < BT; ++b)
            hv[b] = *(const float4*)(Bl + b * LD + k0 + c2 * 4);
#pragma unroll
        for (int jj = 0; jj < 3; ++jj) {
#pragma unroll
            for (int b = 0; b < BT; ++b) {
                acc[jj][b] += W[jj][c2 * 4 + 0] * hv[b].x;
                acc[jj][b] += W[jj][c2 * 4 + 1] * hv[b].y;
                acc[jj][b] += W[jj][c2 * 4 + 2] * hv[b].z;
                acc[jj][b] += W[jj][c2 * 4 + 3] * hv[b].w;
            }
        }
    }

    // transpose-reduce across the 4 kq lanes of each quad.
    // After round 1 (xor 1): even-kq lanes hold b 0..3, odd hold b 4..7 (2 slices summed).
    // After round 2 (xor 2): lane kq holds full sums for b = bown..bown+1 where
    // bown = ((kq&1)<<2) | ((kq>>1)<<1)  ->  kq 0,1,2,3 owns b {0,1},{4,5},{2,3},{6,7}.
    float fin[3][2];
#pragma unroll
    for (int jj = 0; jj < 3; ++jj) {
        float red[4];
#pragma unroll
        for (int b = 0; b < 4; ++b) {
            float lo = acc[jj][b], hi = acc[jj][b + 4];
            float olo = __shfl_xor(lo, 1);
            float ohi = __shfl_xor(hi, 1);
            red[b] = (kq & 1) ? (hi + ohi) : (lo + olo);
        }
#pragma unroll
        for (int r = 0; r < 2; ++r) {
            float lo = red[r], hi = red[r + 2];
            float olo = __shfl_xor(lo, 2);
            float ohi = __shfl_xor(hi, 2);
            fin[jj][r] = (kq & 2) ? (hi + ohi) : (lo + olo);
        }
    }
#pragma unroll
    for (int jj = 0; jj < 3; ++jj) {
        if (jv[jj]) {
#pragma unroll
            for (int r = 0; r < 2; ++r) {
                float v = fin[jj][r] + bias[jj];
                float a = sigm_like(v, isg[jj]);
                sAct[(bown + r) * ACT_LD + jrow[jj]] = a;
            }
        }
    }
}

__global__ __launch_bounds__(256, 1) void lstm_fused(
    const float* __restrict__ x,
    const float* __restrict__ Wih0, const float* __restrict__ Whh0,
    const float* __restrict__ bih0, const float* __restrict__ bhh0,
    const float* __restrict__ Wih1, const float* __restrict__ Whh1,
    const float* __restrict__ bih1, const float* __restrict__ bhh1,
    const float* __restrict__ Wih2, const float* __restrict__ Whh2,
    const float* __restrict__ bih2, const float* __restrict__ bhh2,
    const float* __restrict__ Wout, const float* __restrict__ bout,
    float* __restrict__ out) {
    // LDS buffers. B0 = [x(6) | h0(40) | pad2] stride 48; B1 = [h0 | h1]; B2 = [h1 | h2].
    __shared__ __attribute__((aligned(16))) float sB0[BT * 48];
    __shared__ __attribute__((aligned(16))) float sB1[BT * 80];
    __shared__ __attribute__((aligned(16))) float sB2[BT * 80];
    __shared__ __attribute__((aligned(16))) float sAct[BT * ACT_LD];
    __shared__ __attribute__((aligned(16))) float sY[8 * BT * HID];  // 8-timestep y staging

    const int tid  = threadIdx.x;
    const int jp   = tid >> 2;
    const int kq   = tid & 3;
    const int bown = ((kq & 1) << 2) | ((kq >> 1) << 1);
    const int seq0 = blockIdx.x * BT;

    // ---- persistent weight registers: 3 j-rows x K-quarter per thread ----
    float W0[3][12], W1[3][20], W2[3][20];
    float bias0[3], bias1[3], bias2[3];
    bool  isg[3], jv[3];
    int   jrow[3];
#pragma unroll
    for (int jj = 0; jj < 3; ++jj) {
        int j    = jp * 3 + jj;
        jrow[jj] = j;
        jv[jj]   = (j < G4);
        isg[jj]  = (j >= 2 * HID && j < 3 * HID);  // g-gate rows -> tanh
        if (j < G4) {
#pragma unroll
            for (int k = 0; k < 12; ++k) {
                int   kk = kq * 12 + k;
                float v;
                if (kk < 6)       v = Wih0[j * 6 + kk];
                else if (kk < 46) v = Whh0[j * 40 + (kk - 6)];
                else              v = 0.f;
                W0[jj][k] = v;
            }
#pragma unroll
            for (int k = 0; k < 20; ++k) {
                int kk    = kq * 20 + k;
                W1[jj][k] = (kk < 40) ? Wih1[j * 40 + kk] : Whh1[j * 40 + (kk - 40)];
            }
#pragma unroll
            for (int k = 0; k < 20; ++k) {
                int kk    = kq * 20 + k;
                W2[jj][k] = (kk < 40) ? Wih2[j * 40 + kk] : Whh2[j * 40 + (kk - 40)];
            }
            bias0[jj] = bih0[j] + bhh0[j];
            bias1[jj] = bih1[j] + bhh1[j];
            bias2[jj] = bih2[j] + bhh2[j];
        } else {  // dummy rows 160..191: zero weights, writes suppressed via jv
#pragma unroll
            for (int k = 0; k < 12; ++k) W0[jj][k] = 0.f;
#pragma unroll
            for (int k = 0; k < 20; ++k) { W1[jj][k] = 0.f; W2[jj][k] = 0.f; }
            bias0[jj] = bias1[jj] = bias2[jj] = 0.f;
        }
    }

    // ---- update-phase slots: 320 (b,u) cells on 256 threads ----
    const int  b1 = tid / 40, u1 = tid % 40;
    const bool has2 = (tid < 64);
    const int  s2 = tid + 256;
    const int  b2s = s2 / 40, u2s = s2 % 40;
    float c0a = 0.f, c1a = 0.f, c2a = 0.f;
    float c0b = 0.f, c1b = 0.f, c2b = 0.f;
    const float wo1   = Wout[u1];
    const float wo2   = has2 ? Wout[u2s] : 0.f;
    const float boutv = bout[0];

    // ---- x prefetch lanes ----
    const int    xb = tid / 6, xd = tid % 6;
    const float* xbase = x + (size_t)seq0 * T_LEN * 6;
    float        xr = 0.f;
    if (tid < 48) xr = xbase[xb * (T_LEN * 6) + 0 * 6 + xd];  // x(t=0)

    // zero h state in LDS
    for (int i = tid; i < BT * 48; i += 256) sB0[i] = 0.f;
    for (int i = tid; i < BT * 80; i += 256) sB1[i] = 0.f;
    for (int i = tid; i < BT * 80; i += 256) sB2[i] = 0.f;
    __syncthreads();
    if (tid < 48) {
        sB0[xb * 48 + xd] = xr;                               // store x(0)
        xr = xbase[xb * (T_LEN * 6) + 1 * 6 + xd];            // prefetch x(1)
    }
    __syncthreads();

    for (int t = 0; t < T_LEN; ++t) {
        // A: layer0 gates
        gate_matmul<12, 48>(sB0, W0, bias0, isg, jv, jrow, sAct, kq, bown);
        __syncthreads();
        // B: layer0 cell update + x(t+1) store / x(t+2) prefetch
        {
            float h = cell_update(sAct, b1, u1, c0a);
            sB0[b1 * 48 + 6 + u1] = h;
            sB1[b1 * 80 + u1]     = h;
            if (has2) {
                float h2 = cell_update(sAct, b2s, u2s, c0b);
                sB0[b2s * 48 + 6 + u2s] = h2;
                sB1[b2s * 80 + u2s]     = h2;
            }
            if (tid < 48 && t + 1 < T_LEN) {
                sB0[xb * 48 + xd] = xr;
                if (t + 2 < T_LEN) xr = xbase[xb * (T_LEN * 6) + (t + 2) * 6 + xd];
            }
        }
        __syncthreads();
        // C: layer1 gates
        gate_matmul<20, 80>(sB1, W1, bias1, isg, jv, jrow, sAct, kq, bown);
        __syncthreads();
        // D: layer1 cell update
        {
            float h = cell_update(sAct, b1, u1, c1a);
            sB1[b1 * 80 + 40 + u1] = h;
            sB2[b1 * 80 + u1]      = h;
            if (has2) {
                float h2 = cell_update(sAct, b2s, u2s, c1b);
                sB1[b2s * 80 + 40 + u2s] = h2;
                sB2[b2s * 80 + u2s]      = h2;
            }
        }
        __syncthreads();
        // E: layer2 gates
        gate_matmul<20, 80>(sB2, W2, bias2, isg, jv, jrow, sAct, kq, bown);
        __syncthreads();
        // F: layer2 cell update + y staging
        {
            float h = cell_update(sAct, b1, u1, c2a);
            sB2[b1 * 80 + 40 + u1]            = h;
            sY[(t & 7) * 320 + b1 * 40 + u1]  = h * wo1;
            if (has2) {
                float h2 = cell_update(sAct, b2s, u2s, c2b);
                sB2[b2s * 80 + 40 + u2s]           = h2;
                sY[(t & 7) * 320 + b2s * 40 + u2s] = h2 * wo2;
            }
        }
        __syncthreads();
        // G: every 8 timesteps, reduce sY -> 64 outputs
        if ((t & 7) == 7) {
            int pr = tid >> 2, kq2 = tid & 3;
            int tt = pr >> 3, bb = pr & 7;
            float s = 0.f;
#pragma unroll
            for (int i2 = 0; i2 < 10; ++i2)
                s += sY[tt * 320 + bb * 40 + kq2 * 10 + i2];
            s += __shfl_xor(s, 1);
            s += __shfl_xor(s, 2);
            if (kq2 == 0)
                out[(size_t)(seq0 + bb) * T_LEN + (t - 7) + tt] = s + boutv;
        }
        // no barrier needed: sY[t&7] not rewritten until F(t+1), 5 barriers away
    }
}

extern "C" void kernel_launch(void* const* d_in, const int* in_sizes, int n_in,
                              void* d_out, int out_size, void* d_ws, size_t ws_size,
                              hipStream_t stream) {
    const float* x    = (const float*)d_in[0];
    const float* Wih0 = (const float*)d_in[1];
    const float* Whh0 = (const float*)d_in[2];
    const float* bih0 = (const float*)d_in[3];
    const float* bhh0 = (const float*)d_in[4];
    const float* Wih1 = (const float*)d_in[5];
    const float* Whh1 = (const float*)d_in[6];
    const float* bih1 = (const float*)d_in[7];
    const float* bhh1 = (const float*)d_in[8];
    const float* Wih2 = (const float*)d_in[9];
    const float* Whh2 = (const float*)d_in[10];
    const float* bih2 = (const float*)d_in[11];
    const float* bhh2 = (const float*)d_in[12];
    const float* Wout = (const float*)d_in[13];
    const float* bout = (const float*)d_in[14];

    lstm_fused<<<dim3(2048 / BT), dim3(256), 0, stream>>>(
        x, Wih0, Whh0, bih0, bhh0, Wih1, Whh1, bih1, bhh1,
        Wih2, Whh2, bih2, bhh2, Wout, bout, (float*)d_out);
}

// Round 2
// 2719.132 us; speedup vs baseline: 1.0919x; 1.0919x over previous
//
#include <hip/hip_runtime.h>

#define T_LEN 512
#define HID   40
#define G4    160   // 4*H
#define BT    4     // sequences per block (4 -> 512 blocks -> 2 blocks/CU)
#define ACT_LD 164  // padded act row stride

__device__ __forceinline__ float fast_rcp(float v) { return __builtin_amdgcn_rcpf(v); }

// DPP quad_perm butterfly helpers: xor lane^1 / lane^2 within each quad. Pure VALU.
__device__ __forceinline__ float dpp_add_xor1(float x) {
    return x + __int_as_float(__builtin_amdgcn_update_dpp(
                   0, __float_as_int(x), 0xB1 /*quad_perm [1,0,3,2]*/, 0xF, 0xF, true));
}
__device__ __forceinline__ float dpp_add_xor2(float x) {
    return x + __int_as_float(__builtin_amdgcn_update_dpp(
                   0, __float_as_int(x), 0x4E /*quad_perm [2,3,0,1]*/, 0xF, 0xF, true));
}

// sigmoid, or tanh via tanh(x) = 2*sigmoid(2x)-1
__device__ __forceinline__ float sigm_like(float v, bool isg) {
    float xx = isg ? 2.f * v : v;
    float e  = __expf(-xx);
    float s  = fast_rcp(1.f + e);
    return isg ? 2.f * s - 1.f : s;
}
__device__ __forceinline__ float tanh_fast(float v) {
    float e = __expf(-2.f * v);
    return 2.f * fast_rcp(1.f + e) - 1.f;
}

__device__ __forceinline__ float cell_update(const float* sAct, int b, int u, float& c) {
    float i = sAct[b * ACT_LD + u];
    float f = sAct[b * ACT_LD + 40 + u];
    float g = sAct[b * ACT_LD + 80 + u];
    float o = sAct[b * ACT_LD + 120 + u];
    c = f * c + i * g;
    return o * tanh_fast(c);
}

// Gate matmul: thread (jp,kq) computes partials for 3 j-rows over its K-quarter
// for 4 sequences; DPP butterfly-reduce across the quad gives every lane all 4
// full sums; lane kq keeps b=kq, activates, writes LDS act row.
template <int SLICE, int LD>
__device__ __forceinline__ void gate_matmul(const float* __restrict__ Bl,
                                            const float (&W)[3][SLICE],
                                            const float (&bias)[3],
                                            const bool (&isg)[3],
                                            const bool (&jv)[3],
                                            const int (&jrow)[3],
                                            float* __restrict__ sAct,
                                            int kq) {
    float acc[3][BT];
#pragma unroll
    for (int jj = 0; jj < 3; ++jj)
#pragma unroll
        for (int b = 0; b < BT; ++b) acc[jj][b] = 0.f;

    const int k0 = kq * SLICE;
#pragma unroll
    for (int c2 = 0; c2 < SLICE / 4; ++c2) {
        float4 hv[BT];
#pragma unroll
        for (int b = 0; b < BT; ++b)
            hv[b] = *(const float4*)(Bl + b * LD + k0 + c2 * 4);
#pragma unroll
        for (int jj = 0; jj < 3; ++jj) {
#pragma unroll
            for (int b = 0; b < BT; ++b) {
                acc[jj][b] += W[jj][c2 * 4 + 0] * hv[b].x;
                acc[jj][b] += W[jj][c2 * 4 + 1] * hv[b].y;
                acc[jj][b] += W[jj][c2 * 4 + 2] * hv[b].z;
                acc[jj][b] += W[jj][c2 * 4 + 3] * hv[b].w;
            }
        }
    }

#pragma unroll
    for (int jj = 0; jj < 3; ++jj) {
        float s[BT];
#pragma unroll
        for (int b = 0; b < BT; ++b) {
            float v = acc[jj][b];
            v    = dpp_add_xor1(v);
            v    = dpp_add_xor2(v);   // all 4 lanes now hold full sum for b
            s[b] = v;
        }
        // lane kq keeps b = kq
        float lo  = (kq & 1) ? s[1] : s[0];
        float hi  = (kq & 1) ? s[3] : s[2];
        float fin = (kq & 2) ? hi : lo;
        if (jv[jj]) {
            float a = sigm_like(fin + bias[jj], isg[jj]);
            sAct[kq * ACT_LD + jrow[jj]] = a;
        }
    }
}

__global__ __launch_bounds__(256, 2) void lstm_fused(
    const float* __restrict__ x,
    const float* __restrict__ Wih0, const float* __restrict__ Whh0,
    const float* __restrict__ bih0, const float* __restrict__ bhh0,
    const float* __restrict__ Wih1, const float* __restrict__ Whh1,
    const float* __restrict__ bih1, const float* __restrict__ bhh1,
    const float* __restrict__ Wih2, const float* __restrict__ Whh2,
    const float* __restrict__ bih2, const float* __restrict__ bhh2,
    const float* __restrict__ Wout, const float* __restrict__ bout,
    float* __restrict__ out) {
    // B0 = [x(6) | h0(40) | pad2] stride 48; B1 = [h0 | h1]; B2 = [h1 | h2].
    __shared__ __attribute__((aligned(16))) float sB0[BT * 48];
    __shared__ __attribute__((aligned(16))) float sB1[BT * 80];
    __shared__ __attribute__((aligned(16))) float sB2[BT * 80];
    __shared__ __attribute__((aligned(16))) float sAct[BT * ACT_LD];
    __shared__ __attribute__((aligned(16))) float sY[8 * BT * HID];  // 8-step y staging

    const int tid  = threadIdx.x;
    const int jp   = tid >> 2;
    const int kq   = tid & 3;
    const int seq0 = blockIdx.x * BT;

    // ---- persistent weight registers: 3 j-rows x K-quarter per thread ----
    float W0[3][12], W1[3][20], W2[3][20];
    float bias0[3], bias1[3], bias2[3];
    bool  isg[3], jv[3];
    int   jrow[3];
#pragma unroll
    for (int jj = 0; jj < 3; ++jj) {
        int j    = jp * 3 + jj;
        jrow[jj] = j;
        jv[jj]   = (j < G4);
        isg[jj]  = (j >= 2 * HID && j < 3 * HID);  // g-gate rows -> tanh
        if (j < G4) {
#pragma unroll
            for (int k = 0; k < 12; ++k) {
                int   kk = kq * 12 + k;
                float v;
                if (kk < 6)       v = Wih0[j * 6 + kk];
                else if (kk < 46) v = Whh0[j * 40 + (kk - 6)];
                else              v = 0.f;
                W0[jj][k] = v;
            }
#pragma unroll
            for (int k = 0; k < 20; ++k) {
                int kk    = kq * 20 + k;
                W1[jj][k] = (kk < 40) ? Wih1[j * 40 + kk] : Whh1[j * 40 + (kk - 40)];
            }
#pragma unroll
            for (int k = 0; k < 20; ++k) {
                int kk    = kq * 20 + k;
                W2[jj][k] = (kk < 40) ? Wih2[j * 40 + kk] : Whh2[j * 40 + (kk - 40)];
            }
            bias0[jj] = bih0[j] + bhh0[j];
            bias1[jj] = bih1[j] + bhh1[j];
            bias2[jj] = bih2[j] + bhh2[j];
        } else {
#pragma unroll
            for (int k = 0; k < 12; ++k) W0[jj][k] = 0.f;
#pragma unroll
            for (int k = 0; k < 20; ++k) { W1[jj][k] = 0.f; W2[jj][k] = 0.f; }
            bias0[jj] = bias1[jj] = bias2[jj] = 0.f;
        }
    }

    // ---- update-phase slots: 160 (b,u) cells on threads 0..159 ----
    const bool upd = (tid < BT * HID);
    const int  b1 = tid / 40, u1 = tid % 40;
    float c0 = 0.f, c1 = 0.f, c2 = 0.f;
    const float wo1   = upd ? Wout[u1] : 0.f;
    const float boutv = bout[0];

    // ---- x prefetch lanes: 4 seq x 6 d = 24 lanes ----
    const int    xb = tid / 6, xd = tid % 6;
    const float* xbase = x + (size_t)seq0 * T_LEN * 6;
    float        xr = 0.f;
    if (tid < 24) xr = xbase[xb * (T_LEN * 6) + 0 * 6 + xd];  // x(t=0)

    for (int i = tid; i < BT * 48; i += 256) sB0[i] = 0.f;
    for (int i = tid; i < BT * 80; i += 256) sB1[i] = 0.f;
    for (int i = tid; i < BT * 80; i += 256) sB2[i] = 0.f;
    __syncthreads();
    if (tid < 24) {
        sB0[xb * 48 + xd] = xr;                               // store x(0)
        xr = xbase[xb * (T_LEN * 6) + 1 * 6 + xd];            // prefetch x(1)
    }
    __syncthreads();

    for (int t = 0; t < T_LEN; ++t) {
        // A: layer0 gates
        gate_matmul<12, 48>(sB0, W0, bias0, isg, jv, jrow, sAct, kq);
        __syncthreads();
        // B: layer0 cell update + x(t+1) store / x(t+2) prefetch
        if (upd) {
            float h = cell_update(sAct, b1, u1, c0);
            sB0[b1 * 48 + 6 + u1] = h;
            sB1[b1 * 80 + u1]     = h;
        }
        if (tid < 24 && t + 1 < T_LEN) {
            sB0[xb * 48 + xd] = xr;
            if (t + 2 < T_LEN) xr = xbase[xb * (T_LEN * 6) + (t + 2) * 6 + xd];
        }
        __syncthreads();
        // C: layer1 gates
        gate_matmul<20, 80>(sB1, W1, bias1, isg, jv, jrow, sAct, kq);
        __syncthreads();
        // D: layer1 cell update
        if (upd) {
            float h = cell_update(sAct, b1, u1, c1);
            sB1[b1 * 80 + 40 + u1] = h;
            sB2[b1 * 80 + u1]      = h;
        }
        __syncthreads();
        // E: layer2 gates
        gate_matmul<20, 80>(sB2, W2, bias2, isg, jv, jrow, sAct, kq);
        __syncthreads();
        // F: layer2 cell update + y staging
        if (upd) {
            float h = cell_update(sAct, b1, u1, c2);
            sB2[b1 * 80 + 40 + u1]                  = h;
            sY[(t & 7) * (BT * HID) + b1 * 40 + u1] = h * wo1;
        }
        __syncthreads();
        // G: every 8 timesteps, reduce sY -> 32 outputs (8 t x 4 seq)
        if ((t & 7) == 7 && tid < 128) {
            int pr = tid >> 2, kq2 = tid & 3;
            int tt = pr >> 2, bb = pr & 3;
            float s = 0.f;
#pragma unroll
            for (int i2 = 0; i2 < 10; ++i2)
                s += sY[tt * (BT * HID) + bb * 40 + kq2 * 10 + i2];
            s = dpp_add_xor1(s);
            s = dpp_add_xor2(s);
            if (kq2 == 0)
                out[(size_t)(seq0 + bb) * T_LEN + (t - 7) + tt] = s + boutv;
        }
        // no barrier needed: sY slot (t&7) not rewritten until F(t+1), 5 barriers away
    }
}

extern "C" void kernel_launch(void* const* d_in, const int* in_sizes, int n_in,
                              void* d_out, int out_size, void* d_ws, size_t ws_size,
                              hipStream_t stream) {
    const float* x    = (const float*)d_in[0];
    const float* Wih0 = (const float*)d_in[1];
    const float* Whh0 = (const float*)d_in[2];
    const float* bih0 = (const float*)d_in[3];
    const float* bhh0 = (const float*)d_in[4];
    const float* Wih1 = (const float*)d_in[5];
    const float* Whh1 = (const float*)d_in[6];
    const float* bih1 = (const float*)d_in[7];
    const float* bhh1 = (const float*)d_in[8];
    const float* Wih2 = (const float*)d_in[9];
    const float* Whh2 = (const float*)d_in[10];
    const float* bih2 = (const float*)d_in[11];
    const float* bhh2 = (const float*)d_in[12];
    const float* Wout = (const float*)d_in[13];
    const float* bout = (const float*)d_in[14];

    lstm_fused<<<dim3(2048 / BT), dim3(256), 0, stream>>>(
        x, Wih0, Whh0, bih0, bhh0, Wih1, Whh1, bih1, bhh1,
        Wih2, Whh2, bih2, bhh2, Wout, bout, (float*)d_out);
}